// Round 5
// baseline (245.947 us; speedup 1.0000x reference)
//
#include <hip/hip_runtime.h>

// KnowledgeConsistentAttention: out = softmax_q( pool3x3(F) . K^T ) . K,  K = normalize(F+eps)
// pool3x3 acts only on the p index of S = F.K^T => flash-style fused kernel with
// Q=G=pool3x3(F), K=V=normalize(F+eps). exp(S) fits fp32 -> no max subtraction.
//
// R5 = R3 (rt=2, q-tile 32, K double-buffered LDS, 1 barrier/tile) +
//  - V read straight from global as sigma-permuted MFMA fragments (no ldsV, no V DMA)
//  - q-slot permutation sigma(s) = (s>>1) + (s&1)*16 applied to BOTH P-fragment slots and
//    the Vt2 interleave (MFMA contracts slot-wise; consistent relabel is free) -> P-bounce
//    becomes 8 packed u32 writes instead of 16 scalar u16.
//  - registers held to 128 VGPR + 128 AGPR = 2 waves/SIMD.

#define EPSV 1e-7f

typedef __bf16 bf16x8 __attribute__((ext_vector_type(8)));
typedef float f32x4 __attribute__((ext_vector_type(4)));
typedef unsigned short ushort8v __attribute__((ext_vector_type(8)));

__device__ __forceinline__ unsigned short f2bf(float f) {
    union { float f; unsigned int u; } x; x.f = f;
    unsigned int r = x.u + 0x7FFFu + ((x.u >> 16) & 1u);
    return (unsigned short)(r >> 16);
}

__device__ __forceinline__ f32x4 mfma16(bf16x8 a, bf16x8 b, f32x4 c) {
    return __builtin_amdgcn_mfma_f32_16x16x32_bf16(a, b, c, 0, 0, 0);
}

__device__ __forceinline__ void gload_lds16(const void* g, void* l) {
    __builtin_amdgcn_global_load_lds((const __attribute__((address_space(1))) void*)g,
                                     (__attribute__((address_space(3))) void*)l, 16, 0, 0);
}

// ---------------- prep 1: K_hi (bf16 normalized rows) + Vt2 (sigma-permuted fragments) ----
// Vt2: per (b, 32q-tile t, c16): 1KB chunk; lane L = g4*16+l15 holds 16B = 8 bf16:
// V[q0 + sigma(g4*8+e)][c16*16+l15], sigma(s) = (s>>1) + (s&1)*16.
__global__ __launch_bounds__(256) void prep_kv(const float* __restrict__ F,
                                               unsigned short* __restrict__ Khi,
                                               unsigned short* __restrict__ Vt2) {
    __shared__ unsigned short ldsT[256 * 74];  // [c][64q], 148B rows (odd dword stride)
    const int tid = threadIdx.x;
    const int w = tid >> 6, lane = tid & 63;
    const int q0 = blockIdx.x * 64;
    const int b = blockIdx.y;
    const size_t bq = (size_t)b * 4096;

    for (int r = 0; r < 16; ++r) {
        const int qloc = w * 16 + r;
        const int q = q0 + qloc;
        const float4 f = *(const float4*)(F + ((bq + q) << 8) + lane * 4);
        float v0 = f.x + EPSV, v1 = f.y + EPSV, v2 = f.z + EPSV, v3 = f.w + EPSV;
        float ss = v0 * v0 + v1 * v1 + v2 * v2 + v3 * v3;
        #pragma unroll
        for (int m = 1; m <= 32; m <<= 1) ss += __shfl_xor(ss, m);
        const float inv = 1.0f / sqrtf(ss);
        const unsigned short k0 = f2bf(v0 * inv), k1 = f2bf(v1 * inv);
        const unsigned short k2 = f2bf(v2 * inv), k3 = f2bf(v3 * inv);
        ushort4 kk; kk.x = k0; kk.y = k1; kk.z = k2; kk.w = k3;
        *(ushort4*)(Khi + ((bq + q) << 8) + lane * 4) = kk;
        ldsT[(lane * 4 + 0) * 74 + qloc] = k0;
        ldsT[(lane * 4 + 1) * 74 + qloc] = k1;
        ldsT[(lane * 4 + 2) * 74 + qloc] = k2;
        ldsT[(lane * 4 + 3) * 74 + qloc] = k3;
    }
    __syncthreads();
    // thread owns channel c = tid; block covers tiles 2*blockIdx.x, +1
    const int c = tid;
    const int c16v = c >> 4, l15c = c & 15;
    const size_t tbase = (size_t)b * 128 + (size_t)blockIdx.x * 2;
    const unsigned short* row = ldsT + c * 74;
    #pragma unroll
    for (int tsub = 0; tsub < 2; ++tsub) {
        const unsigned short* qrow = row + tsub * 32;
        #pragma unroll
        for (int g4v = 0; g4v < 4; ++g4v) {
            ushort8v frag;
            #pragma unroll
            for (int e = 0; e < 8; ++e)
                frag[e] = qrow[(g4v * 4 + (e >> 1)) + ((e & 1) << 4)];  // sigma
            *(ushort8v*)((char*)Vt2 + ((tbase + tsub) << 14) + (c16v << 10) +
                         ((g4v * 16 + l15c) << 4)) = frag;
        }
    }
}

// ---------------- prep 2: G = pool3x3(F) * 9/cnt (TF SAME), separable, bf16 ----------------
__global__ __launch_bounds__(256) void prep_g(const float* __restrict__ F,
                                              unsigned short* __restrict__ G) {
    __shared__ float vs[64 * 256];
    const int tid = threadIdx.x;
    const int i = blockIdx.x, b = blockIdx.y;
    const size_t bq = (size_t)b * 4096;
    const int i0 = i > 0 ? i - 1 : 0, i1 = i < 63 ? i + 1 : 63;
    #pragma unroll
    for (int k2 = 0; k2 < 16; ++k2) {
        const int cell = k2 * 256 + tid;
        const int j = cell >> 6, c4 = (cell & 63) << 2;
        float4 acc = {0.f, 0.f, 0.f, 0.f};
        for (int ii = i0; ii <= i1; ++ii) {
            const float4 f = *(const float4*)(F + ((bq + ii * 64 + j) << 8) + c4);
            acc.x += f.x; acc.y += f.y; acc.z += f.z; acc.w += f.w;
        }
        *(float4*)(vs + j * 256 + c4) = acc;
    }
    __syncthreads();
    const float ri = (float)(i1 - i0 + 1);
    #pragma unroll
    for (int k2 = 0; k2 < 16; ++k2) {
        const int cell = k2 * 256 + tid;
        const int j = cell >> 6, c4 = (cell & 63) << 2;
        const int j0 = j > 0 ? j - 1 : 0, j1 = j < 63 ? j + 1 : 63;
        float4 s = {0.f, 0.f, 0.f, 0.f};
        for (int jj = j0; jj <= j1; ++jj) {
            const float4 v = *(const float4*)(vs + jj * 256 + c4);
            s.x += v.x; s.y += v.y; s.z += v.z; s.w += v.w;
        }
        const float scale = 9.0f / (ri * (float)(j1 - j0 + 1));
        ushort4 gv; gv.x = f2bf(s.x * scale); gv.y = f2bf(s.y * scale);
        gv.z = f2bf(s.z * scale); gv.w = f2bf(s.w * scale);
        *(ushort4*)(G + ((bq + i * 64 + j) << 8) + c4) = gv;
    }
}

// ---------------- main fused attention ----------------
// grid 512 (XCD-swizzled -> pb[32] x split[4] x b[4]), 256 threads (4 waves, 32p each).
// Per 32q tile: K staged to LDS (dbuf, 1 barrier); S = G@K^T (A=G regs, B=K lds);
// exp -> packed-u32 P bounce (sigma slot order); O^T += V@P with V-frags from global Vt2
// (coalesced 1KB/instr, L1-hot, 4-deep rolling prefetch).
template <int ATOMIC>
__global__ __launch_bounds__(256, 2) void attn_main(
        const unsigned short* __restrict__ Khi, const unsigned short* __restrict__ Vt2,
        const unsigned short* __restrict__ G, float* __restrict__ wsl,
        float* __restrict__ dOut, float* __restrict__ wsO) {
    __shared__ unsigned short ldsK[2][32 * 256];  // 2 x 16KB, granule-XOR swizzle
    __shared__ unsigned int ldsP[4][32 * 20];     // 10KB, per-wave P, 80B rows, sigma slots
    const int tid = threadIdx.x;
    const int w = tid >> 6, lane = tid & 63;
    const int l15 = lane & 15, g4 = lane >> 4;

    // XCD-aware decomposition: all 32 pb of a (split,b) group land on one XCD
    const int bid = blockIdx.x;
    const int u = bid & 7, v = bid >> 3;
    const int group = u * 2 + (v >> 5);
    const int pb = v & 31;
    const int split = group >> 2, b = group & 3;

    const int pw = pb * 128 + w * 32;
    const size_t bq = (size_t)b * 4096;

    const char* KhiB = (const char*)Khi + ((bq + split * 1024) << 9);
    const char* Vt2B = (const char*)Vt2 + (((size_t)b * 128 + split * 32) << 14) + lane * 16;

    // prologue: stage K tile 0 into buf 0
    #pragma unroll
    for (int it = 0; it < 4; ++it) {
        const int g = it * 256 + tid;
        const int row = g >> 5, pos = g & 31;
        gload_lds16(KhiB + row * 512 + ((pos ^ (row & 7)) << 4),
                    (char*)&ldsK[0][0] + g * 16);
    }

    // preload G A-frags: 32 rows x 256 k per wave -> 64 VGPRs
    bf16x8 a[2][8];
    #pragma unroll
    for (int rt = 0; rt < 2; ++rt)
        #pragma unroll
        for (int kg = 0; kg < 8; ++kg)
            a[rt][kg] = *(const bf16x8*)(G + ((bq + pw + rt * 16 + l15) << 8) + (kg << 5) + (g4 << 3));

    f32x4 o[2][16];
    float lacc[2][4];
    #pragma unroll
    for (int rt = 0; rt < 2; ++rt) {
        #pragma unroll
        for (int c16 = 0; c16 < 16; ++c16) o[rt][c16] = f32x4{0.f, 0.f, 0.f, 0.f};
        #pragma unroll
        for (int r = 0; r < 4; ++r) lacc[rt][r] = 0.f;
    }
    unsigned int* Pw = &ldsP[w][0];

    __syncthreads();  // K(0) landed

    #pragma unroll 1
    for (int t = 0; t < 32; ++t) {
        const int cur = t & 1;

        // issue stage of K(t+1) (drained by end-of-iter barrier, a full tile away)
        if (t < 31) {
            const char* ks = KhiB + (size_t)(t + 1) * 16384;
            #pragma unroll
            for (int it = 0; it < 4; ++it) {
                const int g = it * 256 + tid;
                const int row = g >> 5, pos = g & 31;
                gload_lds16(ks + row * 512 + ((pos ^ (row & 7)) << 4),
                            (char*)&ldsK[cur ^ 1][0] + g * 16);
            }
        }

        // issue first 4 V-fragments (latency hidden under GEMM1)
        const char* vt = Vt2B + ((size_t)t << 14);
        bf16x8 bva[4];
        #pragma unroll
        for (int g = 0; g < 4; ++g)
            bva[g] = *(const bf16x8*)(vt + g * 1024);

        // ---- GEMM1: S[32p x 32q] ----
        f32x4 s[2][2];
        #pragma unroll
        for (int rt = 0; rt < 2; ++rt) {
            s[rt][0] = f32x4{0.f, 0.f, 0.f, 0.f};
            s[rt][1] = f32x4{0.f, 0.f, 0.f, 0.f};
        }
        __builtin_amdgcn_s_setprio(1);
        #pragma unroll
        for (int kg = 0; kg < 8; ++kg) {
            #pragma unroll
            for (int ct = 0; ct < 2; ++ct) {
                const int qr = ct * 16 + l15;
                const bf16x8 bk = *(const bf16x8*)((const char*)&ldsK[cur][0] + (qr << 9) +
                                    ((((kg << 2) + g4)) ^ (qr & 7)) * 16);
                s[0][ct] = mfma16(a[0][kg], bk, s[0][ct]);
                s[1][ct] = mfma16(a[1][kg], bk, s[1][ct]);
            }
        }
        __builtin_amdgcn_s_setprio(0);

        // ---- exp + l accum + packed P writes (sigma slot order: pair (q, q+16)) ----
        #pragma unroll
        for (int rt = 0; rt < 2; ++rt)
            #pragma unroll
            for (int r = 0; r < 4; ++r) {
                const float e0 = __expf(s[rt][0][r]);
                const float e1 = __expf(s[rt][1][r]);
                lacc[rt][r] += e0 + e1;
                Pw[(rt * 16 + g4 * 4 + r) * 20 + l15] =
                    (unsigned int)f2bf(e0) | ((unsigned int)f2bf(e1) << 16);
            }

        // ---- GEMM2 (O^T): A = V-frag (global, sigma), B = P-frag (LDS, sigma) ----
        bf16x8 a2[2];
        a2[0] = *(const bf16x8*)((const char*)Pw + l15 * 80 + (g4 << 4));
        a2[1] = *(const bf16x8*)((const char*)Pw + (16 + l15) * 80 + (g4 << 4));
        #pragma unroll
        for (int grp = 0; grp < 4; ++grp) {
            bf16x8 n0, n1, n2, n3;
            if (grp < 3) {
                n0 = *(const bf16x8*)(vt + (grp * 4 + 4) * 1024);
                n1 = *(const bf16x8*)(vt + (grp * 4 + 5) * 1024);
                n2 = *(const bf16x8*)(vt + (grp * 4 + 6) * 1024);
                n3 = *(const bf16x8*)(vt + (grp * 4 + 7) * 1024);
            }
            #pragma unroll
            for (int uu = 0; uu < 4; ++uu) {
                const int c16 = grp * 4 + uu;
                o[0][c16] = mfma16(bva[uu], a2[0], o[0][c16]);
                o[1][c16] = mfma16(bva[uu], a2[1], o[1][c16]);
            }
            if (grp < 3) { bva[0] = n0; bva[1] = n1; bva[2] = n2; bva[3] = n3; }
        }

        if (t < 31) __syncthreads();  // K(t+1) staged + buffer handoff
    }

    // ---- epilogue: reduce l across 16 q-columns ----
    #pragma unroll
    for (int rt = 0; rt < 2; ++rt)
        #pragma unroll
        for (int r = 0; r < 4; ++r) {
            float vsum = lacc[rt][r];
            #pragma unroll
            for (int m = 1; m <= 8; m <<= 1) vsum += __shfl_xor(vsum, m);
            lacc[rt][r] = vsum;
        }
    if (l15 == 0) {
        #pragma unroll
        for (int rt = 0; rt < 2; ++rt)
            #pragma unroll
            for (int r = 0; r < 4; ++r)
                wsl[(size_t)split * 16384 + bq + pw + rt * 16 + g4 * 4 + r] = lacc[rt][r];
    }

    // O^T D-layout: p = pw + rt*16 + l15, c = c16*16 + g4*4 + r -> float4 coalesced stores
    if (!ATOMIC) {
        float* dst = (split == 0) ? dOut : (wsO + (size_t)(split - 1) * 4194304);
        #pragma unroll
        for (int rt = 0; rt < 2; ++rt)
            #pragma unroll
            for (int c16 = 0; c16 < 16; ++c16)
                *(f32x4*)(dst + ((bq + pw + rt * 16 + l15) << 8) + c16 * 16 + (g4 << 2)) = o[rt][c16];
    } else {
        #pragma unroll
        for (int rt = 0; rt < 2; ++rt)
            #pragma unroll
            for (int c16 = 0; c16 < 16; ++c16)
                #pragma unroll
                for (int r = 0; r < 4; ++r) {
                    const size_t idx = ((bq + pw + rt * 16 + l15) << 8) + c16 * 16 + (g4 << 2) + r;
                    atomicAdd(&dOut[idx], o[rt][c16][r]);
                }
    }
}

// ---------------- finalize: sum q-split partials, divide by l ----------------
__global__ __launch_bounds__(256) void reduce_fin(float* __restrict__ dOut,
                                                  const float* __restrict__ wsO,
                                                  const float* __restrict__ wsl) {
    const int i4 = blockIdx.x * 256 + threadIdx.x;
    const int row = i4 >> 6;
    const float l = wsl[row] + wsl[16384 + row] + wsl[32768 + row] + wsl[49152 + row];
    const float inv = 1.0f / l;
    float4 v = ((const float4*)dOut)[i4];
    const float4 a = ((const float4*)wsO)[i4];
    const float4 b = ((const float4*)(wsO + 4194304))[i4];
    const float4 c = ((const float4*)(wsO + 8388608))[i4];
    v.x = (v.x + a.x + b.x + c.x) * inv;
    v.y = (v.y + a.y + b.y + c.y) * inv;
    v.z = (v.z + a.z + b.z + c.z) * inv;
    v.w = (v.w + a.w + b.w + c.w) * inv;
    ((float4*)dOut)[i4] = v;
}

__global__ __launch_bounds__(256) void divide_fin(float* __restrict__ dOut,
                                                  const float* __restrict__ wsl) {
    const int i4 = blockIdx.x * 256 + threadIdx.x;
    const int row = i4 >> 6;
    const float l = wsl[row] + wsl[16384 + row] + wsl[32768 + row] + wsl[49152 + row];
    const float inv = 1.0f / l;
    float4 v = ((const float4*)dOut)[i4];
    v.x *= inv; v.y *= inv; v.z *= inv; v.w *= inv;
    ((float4*)dOut)[i4] = v;
}

extern "C" void kernel_launch(void* const* d_in, const int* in_sizes, int n_in,
                              void* d_out, int out_size, void* d_ws, size_t ws_size,
                              hipStream_t stream) {
    const float* F = (const float*)d_in[0];
    // d_in[1] (masks) has no effect on the output.
    float* out = (float*)d_out;
    char* ws = (char*)d_ws;

    // ws layout: Khi bf16 [4][4096][256] @0 (8MB) | Vt2 bf16 frag-interleaved (8MB) @8MB |
    //            G bf16 [4][4096][256] @16MB | wsl f32 [4][16384] @24MB (256KB) |
    //            wsO f32 3x[4][4096][256] @24.25MB (48MB)
    unsigned short* Khi = (unsigned short*)ws;
    unsigned short* Vt2 = Khi + 4194304;
    unsigned short* G = Vt2 + 4194304;
    float* wsl = (float*)(ws + 25165824);
    float* wsO = (float*)(ws + 25165824 + 262144);
    const size_t needA = 25165824u + 262144u + 3u * 16777216u;

    prep_kv<<<dim3(64, 4), 256, 0, stream>>>(F, Khi, Vt2);
    prep_g<<<dim3(64, 4), 256, 0, stream>>>(F, G);

    if (ws_size >= needA) {
        attn_main<0><<<dim3(512), 256, 0, stream>>>(Khi, Vt2, G, wsl, out, wsO);
        reduce_fin<<<4096, 256, 0, stream>>>(out, wsO, wsl);
    } else {
        hipMemsetAsync(out, 0, 16777216, stream);
        attn_main<1><<<dim3(512), 256, 0, stream>>>(Khi, Vt2, G, wsl, out, nullptr);
        divide_fin<<<4096, 256, 0, stream>>>(out, wsl);
    }
}

// Round 6
// 138.191 us; speedup vs baseline: 1.7798x; 1.7798x over previous
//
#include <hip/hip_runtime.h>

// KnowledgeConsistentAttention: out = softmax_q( pool3x3(F) . K^T ) . K,  K = normalize(F+eps)
// pool3x3 acts only on the p index of S = F.K^T => flash-style fused kernel with
// Q=G=pool3x3(F), K=V=normalize(F+eps). exp(S) fits fp32 -> no max subtraction.
//
// R6 = R5 (32-MFMA GEMM2, sigma-packed u32 P-bounce, rt=2, q-tile 32, K LDS dbuf,
// 1 barrier/tile) with ONE change: V returns to LDS. The R5 Vt2 fragment image is
// DMA'd linearly (global_load_lds, 16KB/tile contiguous) into a double-buffered ldsV,
// issued a full tile ahead (same schedule as K). The bv read maps the wave's 64 lanes
// bijectively onto one contiguous 1KB chunk -> zero bank conflicts on the V path.

#define EPSV 1e-7f

typedef __bf16 bf16x8 __attribute__((ext_vector_type(8)));
typedef float f32x4 __attribute__((ext_vector_type(4)));
typedef unsigned short ushort8v __attribute__((ext_vector_type(8)));

__device__ __forceinline__ unsigned short f2bf(float f) {
    union { float f; unsigned int u; } x; x.f = f;
    unsigned int r = x.u + 0x7FFFu + ((x.u >> 16) & 1u);
    return (unsigned short)(r >> 16);
}

__device__ __forceinline__ f32x4 mfma16(bf16x8 a, bf16x8 b, f32x4 c) {
    return __builtin_amdgcn_mfma_f32_16x16x32_bf16(a, b, c, 0, 0, 0);
}

__device__ __forceinline__ void gload_lds16(const void* g, void* l) {
    __builtin_amdgcn_global_load_lds((const __attribute__((address_space(1))) void*)g,
                                     (__attribute__((address_space(3))) void*)l, 16, 0, 0);
}

// ---------------- prep 1: K_hi (bf16 normalized rows) + Vt2 (sigma-permuted fragments) ----
// Vt2: per (b, 32q-tile t, c16): 1KB chunk; lane L = g4*16+l15 holds 16B = 8 bf16:
// V[q0 + slot(g4,e)][c16*16+l15], slot(g4,e) = g4*4 + (e>>1) + 16*(e&1).
__global__ __launch_bounds__(256) void prep_kv(const float* __restrict__ F,
                                               unsigned short* __restrict__ Khi,
                                               unsigned short* __restrict__ Vt2) {
    __shared__ unsigned short ldsT[256 * 74];  // [c][64q], 148B rows (odd dword stride)
    const int tid = threadIdx.x;
    const int w = tid >> 6, lane = tid & 63;
    const int q0 = blockIdx.x * 64;
    const int b = blockIdx.y;
    const size_t bq = (size_t)b * 4096;

    for (int r = 0; r < 16; ++r) {
        const int qloc = w * 16 + r;
        const int q = q0 + qloc;
        const float4 f = *(const float4*)(F + ((bq + q) << 8) + lane * 4);
        float v0 = f.x + EPSV, v1 = f.y + EPSV, v2 = f.z + EPSV, v3 = f.w + EPSV;
        float ss = v0 * v0 + v1 * v1 + v2 * v2 + v3 * v3;
        #pragma unroll
        for (int m = 1; m <= 32; m <<= 1) ss += __shfl_xor(ss, m);
        const float inv = 1.0f / sqrtf(ss);
        const unsigned short k0 = f2bf(v0 * inv), k1 = f2bf(v1 * inv);
        const unsigned short k2 = f2bf(v2 * inv), k3 = f2bf(v3 * inv);
        ushort4 kk; kk.x = k0; kk.y = k1; kk.z = k2; kk.w = k3;
        *(ushort4*)(Khi + ((bq + q) << 8) + lane * 4) = kk;
        ldsT[(lane * 4 + 0) * 74 + qloc] = k0;
        ldsT[(lane * 4 + 1) * 74 + qloc] = k1;
        ldsT[(lane * 4 + 2) * 74 + qloc] = k2;
        ldsT[(lane * 4 + 3) * 74 + qloc] = k3;
    }
    __syncthreads();
    // thread owns channel c = tid; block covers tiles 2*blockIdx.x, +1
    const int c = tid;
    const int c16v = c >> 4, l15c = c & 15;
    const size_t tbase = (size_t)b * 128 + (size_t)blockIdx.x * 2;
    const unsigned short* row = ldsT + c * 74;
    #pragma unroll
    for (int tsub = 0; tsub < 2; ++tsub) {
        const unsigned short* qrow = row + tsub * 32;
        #pragma unroll
        for (int g4v = 0; g4v < 4; ++g4v) {
            ushort8v frag;
            #pragma unroll
            for (int e = 0; e < 8; ++e)
                frag[e] = qrow[(g4v * 4 + (e >> 1)) + ((e & 1) << 4)];  // sigma slots
            *(ushort8v*)((char*)Vt2 + ((tbase + tsub) << 14) + (c16v << 10) +
                         ((g4v * 16 + l15c) << 4)) = frag;
        }
    }
}

// ---------------- prep 2: G = pool3x3(F) * 9/cnt (TF SAME), separable, bf16 ----------------
__global__ __launch_bounds__(256) void prep_g(const float* __restrict__ F,
                                              unsigned short* __restrict__ G) {
    __shared__ float vs[64 * 256];
    const int tid = threadIdx.x;
    const int i = blockIdx.x, b = blockIdx.y;
    const size_t bq = (size_t)b * 4096;
    const int i0 = i > 0 ? i - 1 : 0, i1 = i < 63 ? i + 1 : 63;
    #pragma unroll
    for (int k2 = 0; k2 < 16; ++k2) {
        const int cell = k2 * 256 + tid;
        const int j = cell >> 6, c4 = (cell & 63) << 2;
        float4 acc = {0.f, 0.f, 0.f, 0.f};
        for (int ii = i0; ii <= i1; ++ii) {
            const float4 f = *(const float4*)(F + ((bq + ii * 64 + j) << 8) + c4);
            acc.x += f.x; acc.y += f.y; acc.z += f.z; acc.w += f.w;
        }
        *(float4*)(vs + j * 256 + c4) = acc;
    }
    __syncthreads();
    const float ri = (float)(i1 - i0 + 1);
    #pragma unroll
    for (int k2 = 0; k2 < 16; ++k2) {
        const int cell = k2 * 256 + tid;
        const int j = cell >> 6, c4 = (cell & 63) << 2;
        const int j0 = j > 0 ? j - 1 : 0, j1 = j < 63 ? j + 1 : 63;
        float4 s = {0.f, 0.f, 0.f, 0.f};
        for (int jj = j0; jj <= j1; ++jj) {
            const float4 v = *(const float4*)(vs + jj * 256 + c4);
            s.x += v.x; s.y += v.y; s.z += v.z; s.w += v.w;
        }
        const float scale = 9.0f / (ri * (float)(j1 - j0 + 1));
        ushort4 gv; gv.x = f2bf(s.x * scale); gv.y = f2bf(s.y * scale);
        gv.z = f2bf(s.z * scale); gv.w = f2bf(s.w * scale);
        *(ushort4*)(G + ((bq + i * 64 + j) << 8) + c4) = gv;
    }
}

// ---------------- main fused attention ----------------
// grid 512 (XCD-swizzled -> pb[32] x split[4] x b[4]), 256 threads (4 waves, 32p each).
// Per 32q tile: K (swizzled) + V (linear fragment image) DMA'd to LDS double-buffers,
// issued a full tile ahead, drained by the single end-of-tile barrier.
// S = G@K^T (A=G regs); exp -> packed-u32 P bounce (sigma slots); O^T += V@P with both
// operands from LDS (V chunk read = contiguous 1KB per wave -> conflict-free).
template <int ATOMIC>
__global__ __launch_bounds__(256, 2) void attn_main(
        const unsigned short* __restrict__ Khi, const unsigned short* __restrict__ Vt2,
        const unsigned short* __restrict__ G, float* __restrict__ wsl,
        float* __restrict__ dOut, float* __restrict__ wsO) {
    __shared__ unsigned short ldsK[2][32 * 256];  // 2 x 16KB, granule-XOR swizzle
    __shared__ unsigned short ldsV[2][32 * 256];  // 2 x 16KB, linear Vt2 fragment image
    __shared__ unsigned int ldsP[4][32 * 20];     // 10KB, per-wave P, 80B rows, sigma slots
    const int tid = threadIdx.x;
    const int w = tid >> 6, lane = tid & 63;
    const int l15 = lane & 15, g4 = lane >> 4;

    // XCD-aware decomposition: all 32 pb of a (split,b) group land on one XCD
    const int bid = blockIdx.x;
    const int u = bid & 7, v = bid >> 3;
    const int group = u * 2 + (v >> 5);
    const int pb = v & 31;
    const int split = group >> 2, b = group & 3;

    const int pw = pb * 128 + w * 32;
    const size_t bq = (size_t)b * 4096;

    const char* KhiB = (const char*)Khi + ((bq + split * 1024) << 9);
    const char* VtB = (const char*)Vt2 + (((size_t)b * 128 + split * 32) << 14);

    // prologue: stage K(0) (inverse-swizzled source) + V(0) (linear copy) into buf 0
    #pragma unroll
    for (int it = 0; it < 4; ++it) {
        const int g = it * 256 + tid;
        const int row = g >> 5, pos = g & 31;
        gload_lds16(KhiB + row * 512 + ((pos ^ (row & 7)) << 4),
                    (char*)&ldsK[0][0] + g * 16);
    }
    #pragma unroll
    for (int it = 0; it < 4; ++it) {
        const int g = it * 256 + tid;
        gload_lds16(VtB + g * 16, (char*)&ldsV[0][0] + g * 16);
    }

    // preload G A-frags: 32 rows x 256 k per wave -> 64 VGPRs
    bf16x8 a[2][8];
    #pragma unroll
    for (int rt = 0; rt < 2; ++rt)
        #pragma unroll
        for (int kg = 0; kg < 8; ++kg)
            a[rt][kg] = *(const bf16x8*)(G + ((bq + pw + rt * 16 + l15) << 8) + (kg << 5) + (g4 << 3));

    f32x4 o[2][16];
    float lacc[2][4];
    #pragma unroll
    for (int rt = 0; rt < 2; ++rt) {
        #pragma unroll
        for (int c16 = 0; c16 < 16; ++c16) o[rt][c16] = f32x4{0.f, 0.f, 0.f, 0.f};
        #pragma unroll
        for (int r = 0; r < 4; ++r) lacc[rt][r] = 0.f;
    }
    unsigned int* Pw = &ldsP[w][0];

    __syncthreads();  // tile 0 landed

    #pragma unroll 1
    for (int t = 0; t < 32; ++t) {
        const int cur = t & 1;

        // issue stage of K(t+1)+V(t+1) (drained by end-of-iter barrier, a full tile away)
        if (t < 31) {
            const char* ks = KhiB + (size_t)(t + 1) * 16384;
            #pragma unroll
            for (int it = 0; it < 4; ++it) {
                const int g = it * 256 + tid;
                const int row = g >> 5, pos = g & 31;
                gload_lds16(ks + row * 512 + ((pos ^ (row & 7)) << 4),
                            (char*)&ldsK[cur ^ 1][0] + g * 16);
            }
            const char* vs2 = VtB + ((size_t)(t + 1) << 14);
            #pragma unroll
            for (int it = 0; it < 4; ++it) {
                const int g = it * 256 + tid;
                gload_lds16(vs2 + g * 16, (char*)&ldsV[cur ^ 1][0] + g * 16);
            }
        }

        // ---- GEMM1: S[32p x 32q] ----
        f32x4 s[2][2];
        #pragma unroll
        for (int rt = 0; rt < 2; ++rt) {
            s[rt][0] = f32x4{0.f, 0.f, 0.f, 0.f};
            s[rt][1] = f32x4{0.f, 0.f, 0.f, 0.f};
        }
        __builtin_amdgcn_s_setprio(1);
        #pragma unroll
        for (int kg = 0; kg < 8; ++kg) {
            #pragma unroll
            for (int ct = 0; ct < 2; ++ct) {
                const int qr = ct * 16 + l15;
                const bf16x8 bk = *(const bf16x8*)((const char*)&ldsK[cur][0] + (qr << 9) +
                                    ((((kg << 2) + g4)) ^ (qr & 7)) * 16);
                s[0][ct] = mfma16(a[0][kg], bk, s[0][ct]);
                s[1][ct] = mfma16(a[1][kg], bk, s[1][ct]);
            }
        }
        __builtin_amdgcn_s_setprio(0);

        // ---- exp + l accum + packed P writes (sigma slot order: pair (q, q+16)) ----
        #pragma unroll
        for (int rt = 0; rt < 2; ++rt)
            #pragma unroll
            for (int r = 0; r < 4; ++r) {
                const float e0 = __expf(s[rt][0][r]);
                const float e1 = __expf(s[rt][1][r]);
                lacc[rt][r] += e0 + e1;
                Pw[(rt * 16 + g4 * 4 + r) * 20 + l15] =
                    (unsigned int)f2bf(e0) | ((unsigned int)f2bf(e1) << 16);
            }

        // ---- GEMM2 (O^T): A = V-frag (LDS, contiguous 1KB/wave), B = P-frag (LDS) ----
        bf16x8 a2[2];
        a2[0] = *(const bf16x8*)((const char*)Pw + l15 * 80 + (g4 << 4));
        a2[1] = *(const bf16x8*)((const char*)Pw + (16 + l15) * 80 + (g4 << 4));
        const char* vbase = (const char*)&ldsV[cur][0] + ((g4 * 16 + l15) << 4);
        __builtin_amdgcn_s_setprio(1);
        #pragma unroll
        for (int c16 = 0; c16 < 16; ++c16) {
            const bf16x8 bv = *(const bf16x8*)(vbase + c16 * 1024);
            o[0][c16] = mfma16(bv, a2[0], o[0][c16]);
            o[1][c16] = mfma16(bv, a2[1], o[1][c16]);
        }
        __builtin_amdgcn_s_setprio(0);

        if (t < 31) __syncthreads();  // K/V(t+1) staged + buffer handoff
    }

    // ---- epilogue: reduce l across 16 q-columns ----
    #pragma unroll
    for (int rt = 0; rt < 2; ++rt)
        #pragma unroll
        for (int r = 0; r < 4; ++r) {
            float vsum = lacc[rt][r];
            #pragma unroll
            for (int m = 1; m <= 8; m <<= 1) vsum += __shfl_xor(vsum, m);
            lacc[rt][r] = vsum;
        }
    if (l15 == 0) {
        #pragma unroll
        for (int rt = 0; rt < 2; ++rt)
            #pragma unroll
            for (int r = 0; r < 4; ++r)
                wsl[(size_t)split * 16384 + bq + pw + rt * 16 + g4 * 4 + r] = lacc[rt][r];
    }

    // O^T D-layout: p = pw + rt*16 + l15, c = c16*16 + g4*4 + r -> float4 coalesced stores
    if (!ATOMIC) {
        float* dst = (split == 0) ? dOut : (wsO + (size_t)(split - 1) * 4194304);
        #pragma unroll
        for (int rt = 0; rt < 2; ++rt)
            #pragma unroll
            for (int c16 = 0; c16 < 16; ++c16)
                *(f32x4*)(dst + ((bq + pw + rt * 16 + l15) << 8) + c16 * 16 + (g4 << 2)) = o[rt][c16];
    } else {
        #pragma unroll
        for (int rt = 0; rt < 2; ++rt)
            #pragma unroll
            for (int c16 = 0; c16 < 16; ++c16)
                #pragma unroll
                for (int r = 0; r < 4; ++r) {
                    const size_t idx = ((bq + pw + rt * 16 + l15) << 8) + c16 * 16 + (g4 << 2) + r;
                    atomicAdd(&dOut[idx], o[rt][c16][r]);
                }
    }
}

// ---------------- finalize: sum q-split partials, divide by l ----------------
__global__ __launch_bounds__(256) void reduce_fin(float* __restrict__ dOut,
                                                  const float* __restrict__ wsO,
                                                  const float* __restrict__ wsl) {
    const int i4 = blockIdx.x * 256 + threadIdx.x;
    const int row = i4 >> 6;
    const float l = wsl[row] + wsl[16384 + row] + wsl[32768 + row] + wsl[49152 + row];
    const float inv = 1.0f / l;
    float4 v = ((const float4*)dOut)[i4];
    const float4 a = ((const float4*)wsO)[i4];
    const float4 b = ((const float4*)(wsO + 4194304))[i4];
    const float4 c = ((const float4*)(wsO + 8388608))[i4];
    v.x = (v.x + a.x + b.x + c.x) * inv;
    v.y = (v.y + a.y + b.y + c.y) * inv;
    v.z = (v.z + a.z + b.z + c.z) * inv;
    v.w = (v.w + a.w + b.w + c.w) * inv;
    ((float4*)dOut)[i4] = v;
}

__global__ __launch_bounds__(256) void divide_fin(float* __restrict__ dOut,
                                                  const float* __restrict__ wsl) {
    const int i4 = blockIdx.x * 256 + threadIdx.x;
    const int row = i4 >> 6;
    const float l = wsl[row] + wsl[16384 + row] + wsl[32768 + row] + wsl[49152 + row];
    const float inv = 1.0f / l;
    float4 v = ((const float4*)dOut)[i4];
    v.x *= inv; v.y *= inv; v.z *= inv; v.w *= inv;
    ((float4*)dOut)[i4] = v;
}

extern "C" void kernel_launch(void* const* d_in, const int* in_sizes, int n_in,
                              void* d_out, int out_size, void* d_ws, size_t ws_size,
                              hipStream_t stream) {
    const float* F = (const float*)d_in[0];
    // d_in[1] (masks) has no effect on the output.
    float* out = (float*)d_out;
    char* ws = (char*)d_ws;

    // ws layout: Khi bf16 [4][4096][256] @0 (8MB) | Vt2 bf16 frag-interleaved (8MB) @8MB |
    //            G bf16 [4][4096][256] @16MB | wsl f32 [4][16384] @24MB (256KB) |
    //            wsO f32 3x[4][4096][256] @24.25MB (48MB)
    unsigned short* Khi = (unsigned short*)ws;
    unsigned short* Vt2 = Khi + 4194304;
    unsigned short* G = Vt2 + 4194304;
    float* wsl = (float*)(ws + 25165824);
    float* wsO = (float*)(ws + 25165824 + 262144);
    const size_t needA = 25165824u + 262144u + 3u * 16777216u;

    prep_kv<<<dim3(64, 4), 256, 0, stream>>>(F, Khi, Vt2);
    prep_g<<<dim3(64, 4), 256, 0, stream>>>(F, G);

    if (ws_size >= needA) {
        attn_main<0><<<dim3(512), 256, 0, stream>>>(Khi, Vt2, G, wsl, out, wsO);
        reduce_fin<<<4096, 256, 0, stream>>>(out, wsO, wsl);
    } else {
        hipMemsetAsync(out, 0, 16777216, stream);
        attn_main<1><<<dim3(512), 256, 0, stream>>>(Khi, Vt2, G, wsl, out, nullptr);
        divide_fin<<<4096, 256, 0, stream>>>(out, wsl);
    }
}

// Round 7
// 126.040 us; speedup vs baseline: 1.9513x; 1.0964x over previous
//
#include <hip/hip_runtime.h>

// KnowledgeConsistentAttention: out = softmax_q( pool3x3(F) . K^T ) . K,  K = normalize(F+eps)
// pool3x3 acts only on the p index of S = F.K^T => flash-style fused kernel with
// Q=G=pool3x3(F), K=V=normalize(F+eps). exp(S) fits fp32 -> no max subtraction.
//
// R7 = R6 + K fragment image: Khi2 stores K pre-arranged in MFMA B-fragment order
// (16 chunks x 1KB per 32q tile, lane L at L*16). Staging is a linear DMA copy and
// every GEMM1 B-read is a contiguous 1KB wave read (the proven conflict-free V pattern).
// Also: native bf16 converts in the exp path; a2 reads hoisted so the P-bounce wait
// for rt0 overlaps rt1's exp work.

#define EPSV 1e-7f

typedef __bf16 bf16x8 __attribute__((ext_vector_type(8)));
typedef float f32x4 __attribute__((ext_vector_type(4)));
typedef unsigned short ushort8v __attribute__((ext_vector_type(8)));

__device__ __forceinline__ unsigned short f2bf(float f) {
    union { float f; unsigned int u; } x; x.f = f;
    unsigned int r = x.u + 0x7FFFu + ((x.u >> 16) & 1u);
    return (unsigned short)(r >> 16);
}

__device__ __forceinline__ f32x4 mfma16(bf16x8 a, bf16x8 b, f32x4 c) {
    return __builtin_amdgcn_mfma_f32_16x16x32_bf16(a, b, c, 0, 0, 0);
}

__device__ __forceinline__ void gload_lds16(const void* g, void* l) {
    __builtin_amdgcn_global_load_lds((const __attribute__((address_space(1))) void*)g,
                                     (__attribute__((address_space(3))) void*)l, 16, 0, 0);
}

// ---------------- prep 1: Khi2 (B-fragment image) + Vt2 (A-fragment image) ----------------
// Khi2: per (b, 32q-tile t, chunk = kg*2+ct): 1KB; lane L holds 16B = 8 bf16:
//   K[t*32 + ct*16 + (L&15)][kg*32 + (L>>4)*8 + e]   (16x16x32 B-operand layout)
// Vt2: per (b, 32q-tile t, c16): 1KB; lane L holds 16B:
//   V[q0 + slot(L>>4, e)][c16*16 + (L&15)], slot(g4,e) = g4*4 + (e>>1) + 16*(e&1).
__global__ __launch_bounds__(256) void prep_kv(const float* __restrict__ F,
                                               unsigned short* __restrict__ Khi2,
                                               unsigned short* __restrict__ Vt2) {
    __shared__ unsigned short ldsT[256 * 74];   // [c][64q], 148B rows (for V gather)
    __shared__ unsigned short ldsR[64 * 264];   // [qloc][c], 528B rows (for K frags)
    const int tid = threadIdx.x;
    const int w = tid >> 6, lane = tid & 63;
    const int q0 = blockIdx.x * 64;
    const int b = blockIdx.y;
    const size_t bq = (size_t)b * 4096;

    for (int r = 0; r < 16; ++r) {
        const int qloc = w * 16 + r;
        const int q = q0 + qloc;
        const float4 f = *(const float4*)(F + ((bq + q) << 8) + lane * 4);
        float v0 = f.x + EPSV, v1 = f.y + EPSV, v2 = f.z + EPSV, v3 = f.w + EPSV;
        float ss = v0 * v0 + v1 * v1 + v2 * v2 + v3 * v3;
        #pragma unroll
        for (int m = 1; m <= 32; m <<= 1) ss += __shfl_xor(ss, m);
        const float inv = 1.0f / sqrtf(ss);
        const unsigned short k0 = f2bf(v0 * inv), k1 = f2bf(v1 * inv);
        const unsigned short k2 = f2bf(v2 * inv), k3 = f2bf(v3 * inv);
        ushort4 kk; kk.x = k0; kk.y = k1; kk.z = k2; kk.w = k3;
        *(ushort4*)(ldsR + qloc * 264 + lane * 4) = kk;
        ldsT[(lane * 4 + 0) * 74 + qloc] = k0;
        ldsT[(lane * 4 + 1) * 74 + qloc] = k1;
        ldsT[(lane * 4 + 2) * 74 + qloc] = k2;
        ldsT[(lane * 4 + 3) * 74 + qloc] = k3;
    }
    __syncthreads();

    const size_t tbase = (size_t)b * 128 + (size_t)blockIdx.x * 2;

    // ---- K fragments from ldsR ----
    #pragma unroll
    for (int tsub = 0; tsub < 2; ++tsub) {
        char* dstK = (char*)Khi2 + ((tbase + tsub) << 14);
        #pragma unroll
        for (int i = 0; i < 4; ++i) {
            const int fi = i * 256 + tid;
            const int chunk = fi >> 6, L = fi & 63;
            const int l15 = L & 15, g4v = L >> 4;
            const int kg = chunk >> 1, ct = chunk & 1;
            const int qloc = tsub * 32 + ct * 16 + l15;
            const int c0 = kg * 32 + g4v * 8;
            *(ushort8v*)(dstK + fi * 16) = *(const ushort8v*)(ldsR + qloc * 264 + c0);
        }
    }

    // ---- V fragments from ldsT (sigma slot order) ----
    const int c = tid;
    const int c16v = c >> 4, l15c = c & 15;
    const unsigned short* row = ldsT + c * 74;
    #pragma unroll
    for (int tsub = 0; tsub < 2; ++tsub) {
        const unsigned short* qrow = row + tsub * 32;
        #pragma unroll
        for (int g4v = 0; g4v < 4; ++g4v) {
            ushort8v frag;
            #pragma unroll
            for (int e = 0; e < 8; ++e)
                frag[e] = qrow[(g4v * 4 + (e >> 1)) + ((e & 1) << 4)];  // sigma slots
            *(ushort8v*)((char*)Vt2 + ((tbase + tsub) << 14) + (c16v << 10) +
                         ((g4v * 16 + l15c) << 4)) = frag;
        }
    }
}

// ---------------- prep 2: G = pool3x3(F) * 9/cnt (TF SAME), separable, bf16 ----------------
__global__ __launch_bounds__(256) void prep_g(const float* __restrict__ F,
                                              unsigned short* __restrict__ G) {
    __shared__ float vs[64 * 256];
    const int tid = threadIdx.x;
    const int i = blockIdx.x, b = blockIdx.y;
    const size_t bq = (size_t)b * 4096;
    const int i0 = i > 0 ? i - 1 : 0, i1 = i < 63 ? i + 1 : 63;
    #pragma unroll
    for (int k2 = 0; k2 < 16; ++k2) {
        const int cell = k2 * 256 + tid;
        const int j = cell >> 6, c4 = (cell & 63) << 2;
        float4 acc = {0.f, 0.f, 0.f, 0.f};
        for (int ii = i0; ii <= i1; ++ii) {
            const float4 f = *(const float4*)(F + ((bq + ii * 64 + j) << 8) + c4);
            acc.x += f.x; acc.y += f.y; acc.z += f.z; acc.w += f.w;
        }
        *(float4*)(vs + j * 256 + c4) = acc;
    }
    __syncthreads();
    const float ri = (float)(i1 - i0 + 1);
    #pragma unroll
    for (int k2 = 0; k2 < 16; ++k2) {
        const int cell = k2 * 256 + tid;
        const int j = cell >> 6, c4 = (cell & 63) << 2;
        const int j0 = j > 0 ? j - 1 : 0, j1 = j < 63 ? j + 1 : 63;
        float4 s = {0.f, 0.f, 0.f, 0.f};
        for (int jj = j0; jj <= j1; ++jj) {
            const float4 v = *(const float4*)(vs + jj * 256 + c4);
            s.x += v.x; s.y += v.y; s.z += v.z; s.w += v.w;
        }
        const float scale = 9.0f / (ri * (float)(j1 - j0 + 1));
        ushort4 gv; gv.x = f2bf(s.x * scale); gv.y = f2bf(s.y * scale);
        gv.z = f2bf(s.z * scale); gv.w = f2bf(s.w * scale);
        *(ushort4*)(G + ((bq + i * 64 + j) << 8) + c4) = gv;
    }
}

// ---------------- main fused attention ----------------
// grid 512 (XCD-swizzled -> pb[32] x split[4] x b[4]), 256 threads (4 waves, 32p each).
// Per 32q tile: K + V fragment images DMA'd linearly to LDS double-buffers, issued a full
// tile ahead, drained by the single end-of-tile barrier. S = G@K^T (A=G regs, B=contiguous
// chunk reads); exp -> packed-u32 P bounce (sigma slots); O^T += V@P (contiguous chunks).
template <int ATOMIC>
__global__ __launch_bounds__(256, 2) void attn_main(
        const unsigned short* __restrict__ Khi2, const unsigned short* __restrict__ Vt2,
        const unsigned short* __restrict__ G, float* __restrict__ wsl,
        float* __restrict__ dOut, float* __restrict__ wsO) {
    __shared__ unsigned short ldsK[2][32 * 256];  // 2 x 16KB, linear fragment image
    __shared__ unsigned short ldsV[2][32 * 256];  // 2 x 16KB, linear fragment image
    __shared__ unsigned int ldsP[4][32 * 20];     // 10KB, per-wave P, 80B rows, sigma slots
    const int tid = threadIdx.x;
    const int w = tid >> 6, lane = tid & 63;
    const int l15 = lane & 15, g4 = lane >> 4;

    // XCD-aware decomposition: all 32 pb of a (split,b) group land on one XCD
    const int bid = blockIdx.x;
    const int u = bid & 7, v = bid >> 3;
    const int group = u * 2 + (v >> 5);
    const int pb = v & 31;
    const int split = group >> 2, b = group & 3;

    const int pw = pb * 128 + w * 32;
    const size_t bq = (size_t)b * 4096;

    const char* KhiB = (const char*)Khi2 + (((size_t)b * 128 + split * 32) << 14);
    const char* VtB = (const char*)Vt2 + (((size_t)b * 128 + split * 32) << 14);

    // prologue: stage K(0) + V(0) (both linear copies) into buf 0
    #pragma unroll
    for (int it = 0; it < 4; ++it) {
        const int g = it * 256 + tid;
        gload_lds16(KhiB + g * 16, (char*)&ldsK[0][0] + g * 16);
    }
    #pragma unroll
    for (int it = 0; it < 4; ++it) {
        const int g = it * 256 + tid;
        gload_lds16(VtB + g * 16, (char*)&ldsV[0][0] + g * 16);
    }

    // preload G A-frags: 32 rows x 256 k per wave -> 64 VGPRs
    bf16x8 a[2][8];
    #pragma unroll
    for (int rt = 0; rt < 2; ++rt)
        #pragma unroll
        for (int kg = 0; kg < 8; ++kg)
            a[rt][kg] = *(const bf16x8*)(G + ((bq + pw + rt * 16 + l15) << 8) + (kg << 5) + (g4 << 3));

    f32x4 o[2][16];
    float lacc[2][4];
    #pragma unroll
    for (int rt = 0; rt < 2; ++rt) {
        #pragma unroll
        for (int c16 = 0; c16 < 16; ++c16) o[rt][c16] = f32x4{0.f, 0.f, 0.f, 0.f};
        #pragma unroll
        for (int r = 0; r < 4; ++r) lacc[rt][r] = 0.f;
    }
    unsigned int* Pw = &ldsP[w][0];

    __syncthreads();  // tile 0 landed

    #pragma unroll 1
    for (int t = 0; t < 32; ++t) {
        const int cur = t & 1;

        // issue stage of K(t+1)+V(t+1) (drained by end-of-iter barrier, a full tile away)
        if (t < 31) {
            const char* ks = KhiB + ((size_t)(t + 1) << 14);
            #pragma unroll
            for (int it = 0; it < 4; ++it) {
                const int g = it * 256 + tid;
                gload_lds16(ks + g * 16, (char*)&ldsK[cur ^ 1][0] + g * 16);
            }
            const char* vs2 = VtB + ((size_t)(t + 1) << 14);
            #pragma unroll
            for (int it = 0; it < 4; ++it) {
                const int g = it * 256 + tid;
                gload_lds16(vs2 + g * 16, (char*)&ldsV[cur ^ 1][0] + g * 16);
            }
        }

        // ---- GEMM1: S[32p x 32q]; B-frags = contiguous 1KB chunk reads ----
        f32x4 s[2][2];
        #pragma unroll
        for (int rt = 0; rt < 2; ++rt) {
            s[rt][0] = f32x4{0.f, 0.f, 0.f, 0.f};
            s[rt][1] = f32x4{0.f, 0.f, 0.f, 0.f};
        }
        const char* kb = (const char*)&ldsK[cur][0] + (lane << 4);
        __builtin_amdgcn_s_setprio(1);
        #pragma unroll
        for (int kg = 0; kg < 8; ++kg) {
            #pragma unroll
            for (int ct = 0; ct < 2; ++ct) {
                const bf16x8 bk = *(const bf16x8*)(kb + (kg * 2 + ct) * 1024);
                s[0][ct] = mfma16(a[0][kg], bk, s[0][ct]);
                s[1][ct] = mfma16(a[1][kg], bk, s[1][ct]);
            }
        }
        __builtin_amdgcn_s_setprio(0);

        // ---- exp + l accum + packed P writes; a2 reads hoisted per rt-phase ----
        bf16x8 a2[2];
        #pragma unroll
        for (int rt = 0; rt < 2; ++rt) {
            #pragma unroll
            for (int r = 0; r < 4; ++r) {
                const float e0 = __expf(s[rt][0][r]);
                const float e1 = __expf(s[rt][1][r]);
                lacc[rt][r] += e0 + e1;
                union { __bf16 h[2]; unsigned int u; } pk;
                pk.h[0] = (__bf16)e0; pk.h[1] = (__bf16)e1;
                Pw[(rt * 16 + g4 * 4 + r) * 20 + l15] = pk.u;
            }
            a2[rt] = *(const bf16x8*)((const char*)Pw + (rt * 16 + l15) * 80 + (g4 << 4));
        }

        // ---- GEMM2 (O^T): A = V-frag (contiguous 1KB chunk), B = P-frag ----
        const char* vbase = (const char*)&ldsV[cur][0] + (lane << 4);
        __builtin_amdgcn_s_setprio(1);
        #pragma unroll
        for (int c16 = 0; c16 < 16; ++c16) {
            const bf16x8 bv = *(const bf16x8*)(vbase + c16 * 1024);
            o[0][c16] = mfma16(bv, a2[0], o[0][c16]);
            o[1][c16] = mfma16(bv, a2[1], o[1][c16]);
        }
        __builtin_amdgcn_s_setprio(0);

        if (t < 31) __syncthreads();  // K/V(t+1) staged + buffer handoff
    }

    // ---- epilogue: reduce l across 16 q-columns ----
    #pragma unroll
    for (int rt = 0; rt < 2; ++rt)
        #pragma unroll
        for (int r = 0; r < 4; ++r) {
            float vsum = lacc[rt][r];
            #pragma unroll
            for (int m = 1; m <= 8; m <<= 1) vsum += __shfl_xor(vsum, m);
            lacc[rt][r] = vsum;
        }
    if (l15 == 0) {
        #pragma unroll
        for (int rt = 0; rt < 2; ++rt)
            #pragma unroll
            for (int r = 0; r < 4; ++r)
                wsl[(size_t)split * 16384 + bq + pw + rt * 16 + g4 * 4 + r] = lacc[rt][r];
    }

    // O^T D-layout: p = pw + rt*16 + l15, c = c16*16 + g4*4 + r -> float4 coalesced stores
    if (!ATOMIC) {
        float* dst = (split == 0) ? dOut : (wsO + (size_t)(split - 1) * 4194304);
        #pragma unroll
        for (int rt = 0; rt < 2; ++rt)
            #pragma unroll
            for (int c16 = 0; c16 < 16; ++c16)
                *(f32x4*)(dst + ((bq + pw + rt * 16 + l15) << 8) + c16 * 16 + (g4 << 2)) = o[rt][c16];
    } else {
        #pragma unroll
        for (int rt = 0; rt < 2; ++rt)
            #pragma unroll
            for (int c16 = 0; c16 < 16; ++c16)
                #pragma unroll
                for (int r = 0; r < 4; ++r) {
                    const size_t idx = ((bq + pw + rt * 16 + l15) << 8) + c16 * 16 + (g4 << 2) + r;
                    atomicAdd(&dOut[idx], o[rt][c16][r]);
                }
    }
}

// ---------------- finalize: sum q-split partials, divide by l ----------------
__global__ __launch_bounds__(256) void reduce_fin(float* __restrict__ dOut,
                                                  const float* __restrict__ wsO,
                                                  const float* __restrict__ wsl) {
    const int i4 = blockIdx.x * 256 + threadIdx.x;
    const int row = i4 >> 6;
    const float l = wsl[row] + wsl[16384 + row] + wsl[32768 + row] + wsl[49152 + row];
    const float inv = 1.0f / l;
    float4 v = ((const float4*)dOut)[i4];
    const float4 a = ((const float4*)wsO)[i4];
    const float4 b = ((const float4*)(wsO + 4194304))[i4];
    const float4 c = ((const float4*)(wsO + 8388608))[i4];
    v.x = (v.x + a.x + b.x + c.x) * inv;
    v.y = (v.y + a.y + b.y + c.y) * inv;
    v.z = (v.z + a.z + b.z + c.z) * inv;
    v.w = (v.w + a.w + b.w + c.w) * inv;
    ((float4*)dOut)[i4] = v;
}

__global__ __launch_bounds__(256) void divide_fin(float* __restrict__ dOut,
                                                  const float* __restrict__ wsl) {
    const int i4 = blockIdx.x * 256 + threadIdx.x;
    const int row = i4 >> 6;
    const float l = wsl[row] + wsl[16384 + row] + wsl[32768 + row] + wsl[49152 + row];
    const float inv = 1.0f / l;
    float4 v = ((const float4*)dOut)[i4];
    v.x *= inv; v.y *= inv; v.z *= inv; v.w *= inv;
    ((float4*)dOut)[i4] = v;
}

extern "C" void kernel_launch(void* const* d_in, const int* in_sizes, int n_in,
                              void* d_out, int out_size, void* d_ws, size_t ws_size,
                              hipStream_t stream) {
    const float* F = (const float*)d_in[0];
    // d_in[1] (masks) has no effect on the output.
    float* out = (float*)d_out;
    char* ws = (char*)d_ws;

    // ws layout: Khi2 bf16 frag image (8MB) @0 | Vt2 bf16 frag image (8MB) @8MB |
    //            G bf16 [4][4096][256] @16MB | wsl f32 [4][16384] @24MB (256KB) |
    //            wsO f32 3x[4][4096][256] @24.25MB (48MB)
    unsigned short* Khi2 = (unsigned short*)ws;
    unsigned short* Vt2 = Khi2 + 4194304;
    unsigned short* G = Vt2 + 4194304;
    float* wsl = (float*)(ws + 25165824);
    float* wsO = (float*)(ws + 25165824 + 262144);
    const size_t needA = 25165824u + 262144u + 3u * 16777216u;

    prep_kv<<<dim3(64, 4), 256, 0, stream>>>(F, Khi2, Vt2);
    prep_g<<<dim3(64, 4), 256, 0, stream>>>(F, G);

    if (ws_size >= needA) {
        attn_main<0><<<dim3(512), 256, 0, stream>>>(Khi2, Vt2, G, wsl, out, wsO);
        reduce_fin<<<4096, 256, 0, stream>>>(out, wsO, wsl);
    } else {
        hipMemsetAsync(out, 0, 16777216, stream);
        attn_main<1><<<dim3(512), 256, 0, stream>>>(Khi2, Vt2, G, wsl, out, nullptr);
        divide_fin<<<4096, 256, 0, stream>>>(out, wsl);
    }
}